// Round 1
// baseline (450.585 us; speedup 1.0000x reference)
//
#include <hip/hip_runtime.h>
#include <math.h>

// Problem constants (match reference)
#define NQ 16384
#define NK 7933
#define DI 1024
#define HD 512

typedef __bf16 bf16x8 __attribute__((ext_vector_type(8)));
typedef float  f32x4  __attribute__((ext_vector_type(4)));

// ---------------------------------------------------------------------------
// fp32 -> bf16 conversion (8 elems / thread iteration)
// ---------------------------------------------------------------------------
__global__ void f32_to_bf16(const float* __restrict__ src, __bf16* __restrict__ dst, int n8) {
  int i = blockIdx.x * blockDim.x + threadIdx.x;
  int stride = gridDim.x * blockDim.x;
  for (; i < n8; i += stride) {
    float4 a = ((const float4*)src)[2 * i];
    float4 b = ((const float4*)src)[2 * i + 1];
    bf16x8 o;
    o[0] = (__bf16)a.x; o[1] = (__bf16)a.y; o[2] = (__bf16)a.z; o[3] = (__bf16)a.w;
    o[4] = (__bf16)b.x; o[5] = (__bf16)b.y; o[6] = (__bf16)b.z; o[7] = (__bf16)b.w;
    ((bf16x8*)dst)[i] = o;
  }
}

__global__ void zero_f32(float* p, int n) {
  int i = blockIdx.x * blockDim.x + threadIdx.x;
  if (i < n) p[i] = 0.f;
}

// ---------------------------------------------------------------------------
// C[M,512] = tanh(A[M,1024] @ B[512,1024]^T + bias)   (bf16 in, f32 out)
// 128x128 tile, BK=64, 4 waves each doing a 64x64 subtile via 4x4 MFMA 16x16x32
// ---------------------------------------------------------------------------
__global__ __launch_bounds__(256, 2)
void gemm_bt_tanh(const __bf16* __restrict__ A, const __bf16* __restrict__ B,
                  const float* __restrict__ bias, float* __restrict__ C, int M) {
  constexpr int K = DI;
  constexpr int N = HD;
  constexpr int LDSS = 72;  // 64 + 8 pad (keeps 16B alignment, breaks conflicts)
  __shared__ __align__(16) __bf16 sA[128 * LDSS];
  __shared__ __align__(16) __bf16 sB[128 * LDSS];

  const int tid  = threadIdx.x;
  const int lane = tid & 63;
  const int wave = tid >> 6;
  const int wr = wave >> 1, wc = wave & 1;
  const int m0 = blockIdx.x * 128, n0 = blockIdx.y * 128;

  const int srow = tid >> 3;   // 0..31
  const int scb  = tid & 7;    // 0..7  (16B chunk)

  const int lrow = lane & 15;
  const int lko  = (lane >> 4) << 3;  // 0,8,16,24

  f32x4 acc[4][4] = {};

  for (int kk = 0; kk < K; kk += 64) {
    __syncthreads();
#pragma unroll
    for (int rr = 0; rr < 4; ++rr) {
      int row = srow + rr * 32;
      int grow = m0 + row;
      int4 val = make_int4(0, 0, 0, 0);
      if (grow < M) val = *(const int4*)(A + (size_t)grow * K + kk + scb * 8);
      *(int4*)(&sA[row * LDSS + scb * 8]) = val;
    }
#pragma unroll
    for (int rr = 0; rr < 4; ++rr) {
      int row = srow + rr * 32;
      int4 val = *(const int4*)(B + (size_t)(n0 + row) * K + kk + scb * 8);
      *(int4*)(&sB[row * LDSS + scb * 8]) = val;
    }
    __syncthreads();
#pragma unroll
    for (int ks = 0; ks < 64; ks += 32) {
      bf16x8 af[4], bfr[4];
#pragma unroll
      for (int mi = 0; mi < 4; ++mi)
        af[mi] = *(const bf16x8*)(&sA[(wr * 64 + mi * 16 + lrow) * LDSS + ks + lko]);
#pragma unroll
      for (int ni = 0; ni < 4; ++ni)
        bfr[ni] = *(const bf16x8*)(&sB[(wc * 64 + ni * 16 + lrow) * LDSS + ks + lko]);
#pragma unroll
      for (int mi = 0; mi < 4; ++mi)
#pragma unroll
        for (int ni = 0; ni < 4; ++ni)
          acc[mi][ni] = __builtin_amdgcn_mfma_f32_16x16x32_bf16(af[mi], bfr[ni], acc[mi][ni], 0, 0, 0);
    }
  }

  // C/D layout: row = (lane>>4)*4 + reg, col = lane&15  [learn_hip m89]
  const int rbase = m0 + wr * 64 + ((lane >> 4) << 2);
  const int cbase = n0 + wc * 64 + (lane & 15);
#pragma unroll
  for (int mi = 0; mi < 4; ++mi) {
#pragma unroll
    for (int r = 0; r < 4; ++r) {
      int grow = rbase + mi * 16 + r;
      if (grow < M) {
#pragma unroll
        for (int ni = 0; ni < 4; ++ni) {
          int gcol = cbase + ni * 16;
          C[(size_t)grow * N + gcol] = tanhf(acc[mi][ni][r] + bias[gcol]);
        }
      }
    }
  }
}

// ---------------------------------------------------------------------------
// v[512] = sum_k wa[k] * ktanh[k,:] / max(||ktanh[k,:]||, 1e-12)
// one wave per row iteration; per-lane register accumulation of 8 components
// ---------------------------------------------------------------------------
__global__ __launch_bounds__(256)
void reduce_v(const float* __restrict__ kt, const float* __restrict__ wa,
              float* __restrict__ v, int M) {
  __shared__ float vpart[4][512];
  const int tid = threadIdx.x, lane = tid & 63, wave = tid >> 6;
  const int gw = blockIdx.x * 4 + wave;
  const int tw = gridDim.x * 4;
  float acc[8] = {0, 0, 0, 0, 0, 0, 0, 0};
  for (int r = gw; r < M; r += tw) {
    const float4* p = (const float4*)(kt + (size_t)r * HD + lane * 8);
    float4 x = p[0], y = p[1];
    float ss = x.x * x.x + x.y * x.y + x.z * x.z + x.w * x.w
             + y.x * y.x + y.y * y.y + y.z * y.z + y.w * y.w;
#pragma unroll
    for (int off = 32; off; off >>= 1) ss += __shfl_xor(ss, off);
    float s = wa[r] / fmaxf(sqrtf(ss), 1e-12f);
    acc[0] += s * x.x; acc[1] += s * x.y; acc[2] += s * x.z; acc[3] += s * x.w;
    acc[4] += s * y.x; acc[5] += s * y.y; acc[6] += s * y.z; acc[7] += s * y.w;
  }
#pragma unroll
  for (int j = 0; j < 8; ++j) vpart[wave][lane * 8 + j] = acc[j];
  __syncthreads();
  for (int c = tid; c < 512; c += 256)
    atomicAdd(&v[c], vpart[0][c] + vpart[1][c] + vpart[2][c] + vpart[3][c]);
}

// ---------------------------------------------------------------------------
// A1[r] = dot(qtanh[r,:], v) / max(||qtanh[r,:]||,1e-12) + wa_b
// ---------------------------------------------------------------------------
__global__ __launch_bounds__(256)
void compute_a1(const float* __restrict__ qt, const float* __restrict__ v,
                const float* __restrict__ wa_b, float* __restrict__ A1, int M) {
  const int tid = threadIdx.x, lane = tid & 63, wave = tid >> 6;
  const int gw = blockIdx.x * 4 + wave;
  const int tw = gridDim.x * 4;
  const float4* vp = (const float4*)(v + lane * 8);
  const float4 v0 = vp[0], v1 = vp[1];
  const float wab = wa_b[0];
  for (int r = gw; r < M; r += tw) {
    const float4* p = (const float4*)(qt + (size_t)r * HD + lane * 8);
    float4 x = p[0], y = p[1];
    float dot = x.x * v0.x + x.y * v0.y + x.z * v0.z + x.w * v0.w
              + y.x * v1.x + y.y * v1.y + y.z * v1.z + y.w * v1.w;
    float ss  = x.x * x.x + x.y * x.y + x.z * x.z + x.w * x.w
              + y.x * y.x + y.y * y.y + y.z * y.z + y.w * y.w;
#pragma unroll
    for (int off = 32; off; off >>= 1) { dot += __shfl_xor(dot, off); ss += __shfl_xor(ss, off); }
    if (lane == 0) A1[r] = dot / fmaxf(sqrtf(ss), 1e-12f) + wab;
  }
}

// ---------------------------------------------------------------------------
// Exact k-th order statistic (0-based ascending rank `target`) via 4-pass
// MSB radix select on monotone uint mapping. Single block of 256 threads.
// ---------------------------------------------------------------------------
__global__ void radix_select(const float* __restrict__ A1, int n, int target,
                             float* __restrict__ thre_out) {
  __shared__ unsigned int hist[256];
  __shared__ unsigned int s_prefix, s_rank;
  const int tid = threadIdx.x;
  if (tid == 0) { s_prefix = 0u; s_rank = (unsigned)target; }
  __syncthreads();
  for (int pass = 3; pass >= 0; --pass) {
    const int shift = pass * 8;
    hist[tid] = 0u;
    __syncthreads();
    const unsigned prefix = s_prefix;
    const unsigned himask = (pass == 3) ? 0u : (0xFFFFFFFFu << (shift + 8));
    for (int i = tid; i < n; i += 256) {
      unsigned b = __float_as_uint(A1[i]);
      unsigned key = (b & 0x80000000u) ? ~b : (b | 0x80000000u);
      if ((key & himask) == prefix) atomicAdd(&hist[(key >> shift) & 255u], 1u);
    }
    __syncthreads();
    if (tid == 0) {
      unsigned rank = s_rank, cum = 0; int bsel = 0;
      for (int bkt = 0; bkt < 256; ++bkt) {
        unsigned c = hist[bkt];
        if (cum + c > rank) { bsel = bkt; break; }
        cum += c;
      }
      s_rank = rank - cum;
      s_prefix = prefix | ((unsigned)bsel << shift);
    }
    __syncthreads();
  }
  if (tid == 0) {
    unsigned key = s_prefix;
    unsigned bits = (key & 0x80000000u) ? (key ^ 0x80000000u) : ~key;
    *thre_out = __uint_as_float(bits);
  }
}

// ---------------------------------------------------------------------------
// m = max(threshold(A1)), Z = sum exp(x - m).  Single block, 1024 threads.
// sc[0]=thre (in), sc[1]=m (out), sc[2]=Z (out)
// ---------------------------------------------------------------------------
__global__ __launch_bounds__(1024)
void softmax_stats(const float* __restrict__ A1, int n, float* __restrict__ sc) {
  __shared__ float red[16];
  const int tid = threadIdx.x, lane = tid & 63, wave = tid >> 6;
  const float thre = sc[0];
  float lmax = 0.f;  // thresholded array always contains zeros
  for (int i = tid; i < n; i += 1024) {
    float x = A1[i]; x = (x > thre) ? x : 0.f;
    lmax = fmaxf(lmax, x);
  }
#pragma unroll
  for (int off = 32; off; off >>= 1) lmax = fmaxf(lmax, __shfl_xor(lmax, off));
  if (lane == 0) red[wave] = lmax;
  __syncthreads();
  if (tid == 0) {
    float m = red[0];
    for (int i = 1; i < 16; ++i) m = fmaxf(m, red[i]);
    red[0] = m;
  }
  __syncthreads();
  const float m = red[0];
  __syncthreads();
  float lsum = 0.f;
  for (int i = tid; i < n; i += 1024) {
    float x = A1[i]; x = (x > thre) ? x : 0.f;
    lsum += expf(x - m);
  }
#pragma unroll
  for (int off = 32; off; off >>= 1) lsum += __shfl_xor(lsum, off);
  if (lane == 0) red[wave] = lsum;
  __syncthreads();
  if (tid == 0) {
    float s = 0.f;
    for (int i = 0; i < 16; ++i) s += red[i];
    sc[1] = m; sc[2] = s;
  }
}

// ---------------------------------------------------------------------------
// attn[r] = exp(thr(A1[r]) - m)/Z  (written to out);  z += attn[r]*qtanh[r,:]
// ---------------------------------------------------------------------------
__global__ __launch_bounds__(256)
void attn_and_z(const float* __restrict__ A1, const float* __restrict__ qt,
                const float* __restrict__ sc, float* __restrict__ out_attn,
                float* __restrict__ z, int n) {
  __shared__ float vpart[4][512];
  const int tid = threadIdx.x, lane = tid & 63, wave = tid >> 6;
  const float thre = sc[0], m = sc[1], invZ = 1.f / sc[2];
  const int gw = blockIdx.x * 4 + wave;
  const int tw = gridDim.x * 4;
  float acc[8] = {0, 0, 0, 0, 0, 0, 0, 0};
  for (int r = gw; r < n; r += tw) {
    float x = A1[r]; x = (x > thre) ? x : 0.f;
    float a = expf(x - m) * invZ;
    if (lane == 0) out_attn[r] = a;
    const float4* p = (const float4*)(qt + (size_t)r * HD + lane * 8);
    float4 u = p[0], w = p[1];
    acc[0] += a * u.x; acc[1] += a * u.y; acc[2] += a * u.z; acc[3] += a * u.w;
    acc[4] += a * w.x; acc[5] += a * w.y; acc[6] += a * w.z; acc[7] += a * w.w;
  }
#pragma unroll
  for (int j = 0; j < 8; ++j) vpart[wave][lane * 8 + j] = acc[j];
  __syncthreads();
  for (int c = tid; c < 512; c += 256)
    atomicAdd(&z[c], vpart[0][c] + vpart[1][c] + vpart[2][c] + vpart[3][c]);
}

__global__ void final_y(const float* __restrict__ z, const float* __restrict__ cls_w,
                        const float* __restrict__ cls_b, float* __restrict__ out) {
  const int lane = threadIdx.x;  // 64 threads
  const float4* zp = (const float4*)(z + lane * 8);
  const float4* wp = (const float4*)(cls_w + lane * 8);
  float4 a = zp[0], b = zp[1], c = wp[0], d = wp[1];
  float dot = a.x * c.x + a.y * c.y + a.z * c.z + a.w * c.w
            + b.x * d.x + b.y * d.y + b.z * d.z + b.w * d.w;
#pragma unroll
  for (int off = 32; off; off >>= 1) dot += __shfl_xor(dot, off);
  if (lane == 0) out[0] = dot + cls_b[0];
}

// ---------------------------------------------------------------------------
// Workspace layout (bytes). qtanh overlays kbf/ktanh (dead by then).
// Total required: 69,275,904 bytes.
// ---------------------------------------------------------------------------
#define OFF_WQBF 0u
#define OFF_WKBF 1048576u
#define OFF_QBF  2097152u
#define OFF_A1   35651584u
#define OFF_V    35717120u
#define OFF_Z    35719168u
#define OFF_SC   35721216u
#define OFF_KBF  35721472u
#define OFF_KT   51968256u
#define OFF_QT   35721472u

extern "C" void kernel_launch(void* const* d_in, const int* in_sizes, int n_in,
                              void* d_out, int out_size, void* d_ws, size_t ws_size,
                              hipStream_t stream) {
  const float* query = (const float*)d_in[0];
  const float* key_x = (const float*)d_in[1];
  const float* wq_w  = (const float*)d_in[2];
  const float* wq_b  = (const float*)d_in[3];
  const float* wk_w  = (const float*)d_in[4];
  const float* wk_b  = (const float*)d_in[5];
  const float* wa_w  = (const float*)d_in[6];
  const float* wa_b  = (const float*)d_in[7];
  const float* cls_w = (const float*)d_in[8];
  const float* cls_b = (const float*)d_in[9];
  float* out = (float*)d_out;

  char* ws = (char*)d_ws;
  __bf16* wqbf = (__bf16*)(ws + OFF_WQBF);
  __bf16* wkbf = (__bf16*)(ws + OFF_WKBF);
  __bf16* qbf  = (__bf16*)(ws + OFF_QBF);
  float*  A1   = (float*)(ws + OFF_A1);
  float*  v    = (float*)(ws + OFF_V);
  float*  z    = (float*)(ws + OFF_Z);
  float*  sc   = (float*)(ws + OFF_SC);
  __bf16* kbf  = (__bf16*)(ws + OFF_KBF);
  float*  ktанh_unused = nullptr; (void)ktанh_unused;
  float*  ktanh = (float*)(ws + OFF_KT);
  float*  qtanh = (float*)(ws + OFF_QT);

  // zero v (512) and z (512) — contiguous 1024 floats
  zero_f32<<<4, 256, 0, stream>>>(v, 1024);

  f32_to_bf16<<<2048, 256, 0, stream>>>(query, qbf, NQ * DI / 8);
  f32_to_bf16<<<2048, 256, 0, stream>>>(key_x, kbf, NK * DI / 8);
  f32_to_bf16<<<256, 256, 0, stream>>>(wq_w, wqbf, HD * DI / 8);
  f32_to_bf16<<<256, 256, 0, stream>>>(wk_w, wkbf, HD * DI / 8);

  // k side: ktanh = tanh(key @ wk^T + wk_b), then v reduction
  gemm_bt_tanh<<<dim3(62, 4), 256, 0, stream>>>(kbf, wkbf, wk_b, ktanh, NK);
  reduce_v<<<32, 256, 0, stream>>>(ktanh, wa_w, v, NK);

  // q side: qtanh = tanh(query @ wq^T + wq_b)  (overwrites kbf/ktanh region)
  gemm_bt_tanh<<<dim3(128, 4), 256, 0, stream>>>(qbf, wqbf, wq_b, qtanh, NQ);

  compute_a1<<<256, 256, 0, stream>>>(qtanh, v, wa_b, A1, NQ);

  // thre = sort(A1)[NQ - int(0.3*NQ)] = ascending rank 11469
  radix_select<<<1, 256, 0, stream>>>(A1, NQ, NQ - 4915, sc);
  softmax_stats<<<1, 1024, 0, stream>>>(A1, NQ, sc);

  attn_and_z<<<64, 256, 0, stream>>>(A1, qtanh, sc, out + 1, z, NQ);
  final_y<<<1, 64, 0, stream>>>(z, cls_w, cls_b, out);
}

// Round 2
// 311.128 us; speedup vs baseline: 1.4482x; 1.4482x over previous
//
#include <hip/hip_runtime.h>
#include <math.h>

// Problem constants (match reference)
#define NQ 16384
#define NK 7933
#define DI 1024
#define HD 512

typedef __bf16 bf16x8 __attribute__((ext_vector_type(8)));
typedef float  f32x4  __attribute__((ext_vector_type(4)));

#define GLOAD_LDS16(g, l)                                                     \
  __builtin_amdgcn_global_load_lds(                                           \
      (const __attribute__((address_space(1))) void*)(g),                     \
      (__attribute__((address_space(3))) void*)(l), 16, 0, 0)

// ---------------------------------------------------------------------------
// Fused fp32 -> bf16 conversion for query, key, wq_w, wk_w (8 elems / iter)
// ---------------------------------------------------------------------------
__global__ void conv_all(const float* __restrict__ q, const float* __restrict__ k,
                         const float* __restrict__ wq, const float* __restrict__ wk,
                         __bf16* __restrict__ qbf, __bf16* __restrict__ kbf,
                         __bf16* __restrict__ wqbf, __bf16* __restrict__ wkbf) {
  const int NQ8 = NQ * DI / 8;   // 2097152
  const int NK8 = NK * DI / 8;   // 1015424
  const int W8  = HD * DI / 8;   // 65536
  const int total = NQ8 + NK8 + 2 * W8;
  int i = blockIdx.x * blockDim.x + threadIdx.x;
  int stride = gridDim.x * blockDim.x;
  for (; i < total; i += stride) {
    const float* s; __bf16* d; int j;
    if (i < NQ8)            { s = q;  d = qbf;  j = i; }
    else if (i < NQ8 + NK8) { s = k;  d = kbf;  j = i - NQ8; }
    else if (i < NQ8 + NK8 + W8) { s = wq; d = wqbf; j = i - NQ8 - NK8; }
    else                    { s = wk; d = wkbf; j = i - NQ8 - NK8 - W8; }
    float4 a = ((const float4*)s)[2 * j];
    float4 b = ((const float4*)s)[2 * j + 1];
    bf16x8 o;
    o[0] = (__bf16)a.x; o[1] = (__bf16)a.y; o[2] = (__bf16)a.z; o[3] = (__bf16)a.w;
    o[4] = (__bf16)b.x; o[5] = (__bf16)b.y; o[6] = (__bf16)b.z; o[7] = (__bf16)b.w;
    ((bf16x8*)d)[j] = o;
  }
}

__global__ void zero_u32(unsigned* __restrict__ p, int n) {
  int i = blockIdx.x * blockDim.x + threadIdx.x;
  if (i < n) p[i] = 0u;
}

// ---------------------------------------------------------------------------
// C[M,512] = tanh(A[M,1024] @ B[512,1024]^T + bias)   (bf16 in, f32 out)
// 128x128 tile, BK=64, global_load_lds width-16 staging (m97 structure),
// 4 waves each doing a 64x64 subtile via 4x4 MFMA 16x16x32.
// LDS unpadded (wave-uniform dest constraint of global_load_lds).
// ---------------------------------------------------------------------------
__global__ __launch_bounds__(256, 2)
void gemm_bt_tanh(const __bf16* __restrict__ A, const __bf16* __restrict__ B,
                  const float* __restrict__ bias, float* __restrict__ C, int M) {
  constexpr int K = DI;
  constexpr int N = HD;
  __shared__ __align__(16) __bf16 sA[128 * 64];
  __shared__ __align__(16) __bf16 sB[128 * 64];

  const int tid  = threadIdx.x;
  const int lane = tid & 63;
  const int wave = tid >> 6;
  const int wr = wave >> 1, wc = wave & 1;
  const int m0 = blockIdx.x * 128, n0 = blockIdx.y * 128;

  // staging coords: each wave-call covers 8 rows x 64 cols (1 KiB)
  const int srow = lane >> 3;        // 0..7 row within segment
  const int scol = (lane & 7) * 8;   // bf16 col (16B chunks)

  const int lrow = lane & 15;
  const int lko  = (lane >> 4) << 3;  // 0,8,16,24

  f32x4 acc[4][4] = {};

  for (int kk = 0; kk < K; kk += 64) {
    __syncthreads();
#pragma unroll
    for (int c = 0; c < 4; ++c) {
      int seg = wave * 4 + c;             // 0..15, wave-uniform
      int row = seg * 8 + srow;           // 0..127
      int ga = m0 + row; if (ga > M - 1) ga = M - 1;  // clamp tail (rows>=M unused)
      GLOAD_LDS16(A + (size_t)ga * K + kk + scol, &sA[seg * 8 * 64]);
      GLOAD_LDS16(B + (size_t)(n0 + row) * K + kk + scol, &sB[seg * 8 * 64]);
    }
    __syncthreads();
#pragma unroll
    for (int ks = 0; ks < 64; ks += 32) {
      bf16x8 af[4], bfr[4];
#pragma unroll
      for (int mi = 0; mi < 4; ++mi)
        af[mi] = *(const bf16x8*)(&sA[(wr * 64 + mi * 16 + lrow) * 64 + ks + lko]);
#pragma unroll
      for (int ni = 0; ni < 4; ++ni)
        bfr[ni] = *(const bf16x8*)(&sB[(wc * 64 + ni * 16 + lrow) * 64 + ks + lko]);
#pragma unroll
      for (int mi = 0; mi < 4; ++mi)
#pragma unroll
        for (int ni = 0; ni < 4; ++ni)
          acc[mi][ni] = __builtin_amdgcn_mfma_f32_16x16x32_bf16(af[mi], bfr[ni], acc[mi][ni], 0, 0, 0);
    }
  }

  // C/D layout: row = (lane>>4)*4 + reg, col = lane&15  [learn_hip m89]
  const int rbase = m0 + wr * 64 + ((lane >> 4) << 2);
  const int cbase = n0 + wc * 64 + (lane & 15);
#pragma unroll
  for (int mi = 0; mi < 4; ++mi) {
#pragma unroll
    for (int r = 0; r < 4; ++r) {
      int grow = rbase + mi * 16 + r;
      if (grow < M) {
#pragma unroll
        for (int ni = 0; ni < 4; ++ni) {
          int gcol = cbase + ni * 16;
          C[(size_t)grow * N + gcol] = tanhf(acc[mi][ni][r] + bias[gcol]);
        }
      }
    }
  }
}

// ---------------------------------------------------------------------------
// v[512] = sum_k wa[k] * ktanh[k,:] / max(||ktanh[k,:]||, 1e-12)
// ---------------------------------------------------------------------------
__global__ __launch_bounds__(256)
void reduce_v(const float* __restrict__ kt, const float* __restrict__ wa,
              float* __restrict__ v, int M) {
  __shared__ float vpart[4][512];
  const int tid = threadIdx.x, lane = tid & 63, wave = tid >> 6;
  const int gw = blockIdx.x * 4 + wave;
  const int tw = gridDim.x * 4;
  float acc[8] = {0, 0, 0, 0, 0, 0, 0, 0};
  for (int r = gw; r < M; r += tw) {
    const float4* p = (const float4*)(kt + (size_t)r * HD + lane * 8);
    float4 x = p[0], y = p[1];
    float ss = x.x * x.x + x.y * x.y + x.z * x.z + x.w * x.w
             + y.x * y.x + y.y * y.y + y.z * y.z + y.w * y.w;
#pragma unroll
    for (int off = 32; off; off >>= 1) ss += __shfl_xor(ss, off);
    float s = wa[r] / fmaxf(sqrtf(ss), 1e-12f);
    acc[0] += s * x.x; acc[1] += s * x.y; acc[2] += s * x.z; acc[3] += s * x.w;
    acc[4] += s * y.x; acc[5] += s * y.y; acc[6] += s * y.z; acc[7] += s * y.w;
  }
#pragma unroll
  for (int j = 0; j < 8; ++j) vpart[wave][lane * 8 + j] = acc[j];
  __syncthreads();
  for (int c = tid; c < 512; c += 256)
    atomicAdd(&v[c], vpart[0][c] + vpart[1][c] + vpart[2][c] + vpart[3][c]);
}

// ---------------------------------------------------------------------------
// A1[r] = dot(qtanh[r,:], v) / max(||qtanh[r,:]||,1e-12) + wa_b
// ---------------------------------------------------------------------------
__global__ __launch_bounds__(256)
void compute_a1(const float* __restrict__ qt, const float* __restrict__ v,
                const float* __restrict__ wa_b, float* __restrict__ A1, int M) {
  const int tid = threadIdx.x, lane = tid & 63, wave = tid >> 6;
  const int gw = blockIdx.x * 4 + wave;
  const int tw = gridDim.x * 4;
  const float4* vp = (const float4*)(v + lane * 8);
  const float4 v0 = vp[0], v1 = vp[1];
  const float wab = wa_b[0];
  for (int r = gw; r < M; r += tw) {
    const float4* p = (const float4*)(qt + (size_t)r * HD + lane * 8);
    float4 x = p[0], y = p[1];
    float dot = x.x * v0.x + x.y * v0.y + x.z * v0.z + x.w * v0.w
              + y.x * v1.x + y.y * v1.y + y.z * v1.z + y.w * v1.w;
    float ss  = x.x * x.x + x.y * x.y + x.z * x.z + x.w * x.w
              + y.x * y.x + y.y * y.y + y.z * y.z + y.w * y.w;
#pragma unroll
    for (int off = 32; off; off >>= 1) { dot += __shfl_xor(dot, off); ss += __shfl_xor(ss, off); }
    if (lane == 0) A1[r] = dot / fmaxf(sqrtf(ss), 1e-12f) + wab;
  }
}

// ---------------------------------------------------------------------------
// Exact order statistic via two-level 16-bit histograms (grid-parallel).
// Monotone uint mapping: ascending float <=> ascending key.
// ---------------------------------------------------------------------------
__device__ __forceinline__ unsigned mapf(float f) {
  unsigned b = __float_as_uint(f);
  return (b & 0x80000000u) ? ~b : (b | 0x80000000u);
}

__global__ void hist_hi(const float* __restrict__ A1, unsigned* __restrict__ hist) {
  int i = blockIdx.x * blockDim.x + threadIdx.x;
  if (i < NQ) atomicAdd(&hist[mapf(A1[i]) >> 16], 1u);
}

__global__ void hist_lo(const float* __restrict__ A1, const int* __restrict__ sci,
                        unsigned* __restrict__ hist) {
  int i = blockIdx.x * blockDim.x + threadIdx.x;
  if (i < NQ) {
    unsigned key = mapf(A1[i]);
    if ((int)(key >> 16) == sci[0]) atomicAdd(&hist[key & 0xFFFFu], 1u);
  }
}

// Scan 65536-bin histogram, find bin containing `rank` (ascending), store.
// pass 0: rank = NQ-4915 (target order stat); writes sci[0]=hi bin, sci[1]=rem
// pass 1: rank = sci[1]; reconstructs exact float, writes scf[0] = thre
__global__ __launch_bounds__(1024)
void scan_hist(const unsigned* __restrict__ hist, int* __restrict__ sci,
               float* __restrict__ scf, int pass) {
  __shared__ unsigned wsum[16], woff[16];
  const int tid = threadIdx.x, lane = tid & 63, wave = tid >> 6;
  const int base = tid * 64;
  unsigned local = 0;
  for (int j = 0; j < 64; ++j) local += hist[base + j];
  unsigned pre = local;
#pragma unroll
  for (int off = 1; off < 64; off <<= 1) {
    unsigned t = __shfl_up(pre, off);
    if (lane >= off) pre += t;
  }
  if (lane == 63) wsum[wave] = pre;
  __syncthreads();
  if (tid == 0) {
    unsigned c = 0;
    for (int w = 0; w < 16; ++w) { woff[w] = c; c += wsum[w]; }
  }
  __syncthreads();
  const unsigned excl = woff[wave] + pre - local;  // exclusive prefix of this thread's chunk
  const unsigned rank = (pass == 0) ? (unsigned)(NQ - 4915) : (unsigned)sci[1];
  if (local > 0 && rank >= excl && rank < excl + local) {
    unsigned cum = excl;
    for (int j = 0; j < 64; ++j) {
      unsigned c = hist[base + j];
      if (cum + c > rank) {
        if (pass == 0) {
          sci[0] = base + j;
          sci[1] = (int)(rank - cum);
        } else {
          unsigned key = (((unsigned)sci[0]) << 16) | (unsigned)(base + j);
          unsigned bits = (key & 0x80000000u) ? (key ^ 0x80000000u) : ~key;
          scf[0] = __uint_as_float(bits);
        }
        break;
      }
      cum += c;
    }
  }
}

// ---------------------------------------------------------------------------
// Z' = sum exp(thr(A1[i]) - thre)  (softmax is shift-invariant; base = thre)
// ---------------------------------------------------------------------------
__global__ __launch_bounds__(256)
void sum_exp(const float* __restrict__ A1, float* __restrict__ scf) {
  __shared__ float red[4];
  const int tid = threadIdx.x, lane = tid & 63, wave = tid >> 6;
  const float thre = scf[0];
  float s = 0.f;
  for (int i = blockIdx.x * 256 + tid; i < NQ; i += gridDim.x * 256) {
    float x = A1[i]; x = (x > thre) ? x : 0.f;
    s += expf(x - thre);
  }
#pragma unroll
  for (int off = 32; off; off >>= 1) s += __shfl_xor(s, off);
  if (lane == 0) red[wave] = s;
  __syncthreads();
  if (tid == 0) atomicAdd(&scf[2], red[0] + red[1] + red[2] + red[3]);
}

// ---------------------------------------------------------------------------
// attn[r] = exp(thr(A1[r]) - thre)/Z'  ;  z += attn[r]*qtanh[r,:]
// ---------------------------------------------------------------------------
__global__ __launch_bounds__(256)
void attn_and_z(const float* __restrict__ A1, const float* __restrict__ qt,
                const float* __restrict__ scf, float* __restrict__ out_attn,
                float* __restrict__ z, int n) {
  __shared__ float vpart[4][512];
  const int tid = threadIdx.x, lane = tid & 63, wave = tid >> 6;
  const float thre = scf[0], invZ = 1.f / scf[2];
  const int gw = blockIdx.x * 4 + wave;
  const int tw = gridDim.x * 4;
  float acc[8] = {0, 0, 0, 0, 0, 0, 0, 0};
  for (int r = gw; r < n; r += tw) {
    float x = A1[r]; x = (x > thre) ? x : 0.f;
    float a = expf(x - thre) * invZ;
    if (lane == 0) out_attn[r] = a;
    const float4* p = (const float4*)(qt + (size_t)r * HD + lane * 8);
    float4 u = p[0], w = p[1];
    acc[0] += a * u.x; acc[1] += a * u.y; acc[2] += a * u.z; acc[3] += a * u.w;
    acc[4] += a * w.x; acc[5] += a * w.y; acc[6] += a * w.z; acc[7] += a * w.w;
  }
#pragma unroll
  for (int j = 0; j < 8; ++j) vpart[wave][lane * 8 + j] = acc[j];
  __syncthreads();
  for (int c = tid; c < 512; c += 256)
    atomicAdd(&z[c], vpart[0][c] + vpart[1][c] + vpart[2][c] + vpart[3][c]);
}

__global__ void final_y(const float* __restrict__ z, const float* __restrict__ cls_w,
                        const float* __restrict__ cls_b, float* __restrict__ out) {
  const int lane = threadIdx.x;  // 64 threads
  const float4* zp = (const float4*)(z + lane * 8);
  const float4* wp = (const float4*)(cls_w + lane * 8);
  float4 a = zp[0], b = zp[1], c = wp[0], d = wp[1];
  float dot = a.x * c.x + a.y * c.y + a.z * c.z + a.w * c.w
            + b.x * d.x + b.y * d.y + b.z * d.z + b.w * d.w;
#pragma unroll
  for (int off = 32; off; off >>= 1) dot += __shfl_xor(dot, off);
  if (lane == 0) out[0] = dot + cls_b[0];
}

// ---------------------------------------------------------------------------
// Workspace layout (bytes). qtanh overlays kbf/ktanh (dead by then);
// hist1/hist2 overlay wqbf (dead after q-gemm). Total: 69,275,904 bytes.
// ---------------------------------------------------------------------------
#define OFF_WQBF 0u
#define OFF_WKBF 1048576u
#define OFF_QBF  2097152u
#define OFF_A1   35651584u
#define OFF_V    35717120u
#define OFF_Z    35719168u
#define OFF_SC   35721216u
#define OFF_KBF  35721472u
#define OFF_KT   51968256u
#define OFF_QT   35721472u
#define OFF_H1   0u          // 256 KB, overlays wqbf (dead after q-gemm)
#define OFF_H2   262144u     // 256 KB

extern "C" void kernel_launch(void* const* d_in, const int* in_sizes, int n_in,
                              void* d_out, int out_size, void* d_ws, size_t ws_size,
                              hipStream_t stream) {
  const float* query = (const float*)d_in[0];
  const float* key_x = (const float*)d_in[1];
  const float* wq_w  = (const float*)d_in[2];
  const float* wq_b  = (const float*)d_in[3];
  const float* wk_w  = (const float*)d_in[4];
  const float* wk_b  = (const float*)d_in[5];
  const float* wa_w  = (const float*)d_in[6];
  const float* wa_b  = (const float*)d_in[7];
  const float* cls_w = (const float*)d_in[8];
  const float* cls_b = (const float*)d_in[9];
  float* out = (float*)d_out;

  char* ws = (char*)d_ws;
  __bf16* wqbf = (__bf16*)(ws + OFF_WQBF);
  __bf16* wkbf = (__bf16*)(ws + OFF_WKBF);
  __bf16* qbf  = (__bf16*)(ws + OFF_QBF);
  float*  A1   = (float*)(ws + OFF_A1);
  float*  v    = (float*)(ws + OFF_V);
  float*  z    = (float*)(ws + OFF_Z);
  float*  scf  = (float*)(ws + OFF_SC);
  int*    sci  = (int*)(scf + 8);
  __bf16* kbf  = (__bf16*)(ws + OFF_KBF);
  float*  ktanh = (float*)(ws + OFF_KT);
  float*  qtanh = (float*)(ws + OFF_QT);
  unsigned* hist1 = (unsigned*)(ws + OFF_H1);
  unsigned* hist2 = (unsigned*)(ws + OFF_H2);

  // zero v(512) + z(512) + sc(64) — contiguous 1088 u32
  zero_u32<<<5, 256, 0, stream>>>((unsigned*)v, 1088);

  conv_all<<<4096, 256, 0, stream>>>(query, key_x, wq_w, wk_w, qbf, kbf, wqbf, wkbf);

  // k side: ktanh = tanh(key @ wk^T + wk_b), then v reduction
  gemm_bt_tanh<<<dim3(62, 4), 256, 0, stream>>>(kbf, wkbf, wk_b, ktanh, NK);
  reduce_v<<<64, 256, 0, stream>>>(ktanh, wa_w, v, NK);

  // q side: qtanh = tanh(query @ wq^T + wq_b)  (overwrites kbf/ktanh region)
  gemm_bt_tanh<<<dim3(128, 4), 256, 0, stream>>>(qbf, wqbf, wq_b, qtanh, NQ);

  // hists overlay wqbf — zero only after q-gemm
  zero_u32<<<512, 256, 0, stream>>>(hist1, 131072);

  compute_a1<<<256, 256, 0, stream>>>(qtanh, v, wa_b, A1, NQ);

  // thre = sort(A1)[NQ - int(0.3*NQ)] = ascending rank 11469 (exact)
  hist_hi<<<64, 256, 0, stream>>>(A1, hist1);
  scan_hist<<<1, 1024, 0, stream>>>(hist1, sci, scf, 0);
  hist_lo<<<64, 256, 0, stream>>>(A1, sci, hist2);
  scan_hist<<<1, 1024, 0, stream>>>(hist2, sci, scf, 1);

  sum_exp<<<64, 256, 0, stream>>>(A1, scf);
  attn_and_z<<<128, 256, 0, stream>>>(A1, qtanh, scf, out + 1, z, NQ);
  final_y<<<1, 64, 0, stream>>>(z, cls_w, cls_b, out);
}